// Round 5
// baseline (18946.846 us; speedup 1.0000x reference)
//
#include <hip/hip_runtime.h>
#include <stdint.h>

#define B_   512
#define T_   512

typedef __attribute__((ext_vector_type(8))) __bf16 bf16x8;
typedef __attribute__((ext_vector_type(4))) float f32x4;
typedef __attribute__((ext_vector_type(8))) unsigned short u16x8;

// Layer geometry:
//   l : S   | C   | NPT | KT | XOFF | RS (LDS row stride, elems)
//   0 : 231 | 232 | 15  | 8  | 1    | 280
//   1 : 153 | 384 | 10  | 12 | 231  | 408
//   2 : 128 | 281 | 8   | 9  | 153  | 312
// Packed weights (bf16) in d_ws: per layer, 3 matrices (G1=W1*mask, G2=W2*mask, G3=Wa+Wb),
// chunk c = ((m*NPT + nt)*KT + kt)*64 + lane, 8 bf16:
//   elem i = G[nt*16 + (lane&15)][kt*32 + (lane>>4)*8 + i]  (zero outside S x C)
// Layer elem offsets: L0=0, L1=184320, L2=368640.
//
// 16 waves (1024 thr): L0 tile w (w15 dups 14) | L1 tile w, w<10 | L2 tile w-8, w>=8.

#define RS0 280
#define RS1 408
#define RS2 312

__device__ __forceinline__ uint16_t bfbits(float f){
  __bf16 h = (__bf16)f;
  return __builtin_bit_cast(uint16_t, h);
}
__device__ __forceinline__ float bf2f(uint16_t h){
  union { uint32_t u; float f; } v; v.u = ((uint32_t)h) << 16;
  return v.f;
}
__device__ __forceinline__ float sigm_f(float x){
  return __builtin_amdgcn_rcpf(1.0f + __builtin_amdgcn_exp2f(-1.4426950408889634f * x));
}
__device__ __forceinline__ float tanh_f(float x){
  return 2.0f * __builtin_amdgcn_rcpf(1.0f + __builtin_amdgcn_exp2f(-2.8853900817779268f * x)) - 1.0f;
}

// lgkm-only barrier: LDS drained, global weight loads stay in flight.
#define BAR() do { asm volatile("s_waitcnt lgkmcnt(0)" ::: "memory"); \
                   __builtin_amdgcn_s_barrier(); } while(0)

__global__ void pack_w(const float* __restrict__ W1, const float* __restrict__ W2,
                       const float* __restrict__ Wa, const float* __restrict__ Wb,
                       const float* __restrict__ Msk, uint16_t* __restrict__ dst,
                       int NPT, int KT, int S, int C)
{
  int c = blockIdx.x * 256 + threadIdx.x;
  int chunks = 3 * NPT * KT * 64;
  if (c >= chunks) return;
  int perN = KT * 64;
  int n3 = c / perN, r = c % perN;
  int kt = r >> 6, lane = r & 63;
  int m = n3 / NPT, nt = n3 % NPT;
  int j = nt * 16 + (lane & 15);
  int kb = kt * 32 + (lane >> 4) * 8;
  u16x8 o;
  #pragma unroll
  for (int i = 0; i < 8; ++i){
    int k = kb + i;
    float v = 0.f;
    if (j < S && k < C){
      size_t idx = (size_t)j * C + k;
      if (m == 0)      v = W1[idx] * Msk[idx];
      else if (m == 1) v = W2[idx] * Msk[idx];
      else             v = Wa[idx] + Wb[idx];
    }
    o[i] = bfbits(v);
  }
  *(u16x8*)(dst + (size_t)c * 8) = o;
}

template<int KT> struct WG { bf16x8 v[KT]; };

template<int KT>
__device__ __forceinline__ void wload(const bf16x8* __restrict__ p, WG<KT>& g){
  #pragma unroll
  for (int k = 0; k < KT; ++k) g.v[k] = p[k * 64];
}
template<int KT>
__device__ __forceinline__ void wmfma(const bf16x8* a, const WG<KT>& g, f32x4& ac){
  #pragma unroll
  for (int k = 0; k < KT; ++k)
    ac = __builtin_amdgcn_mfma_f32_16x16x32_bf16(a[k], g.v[k], ac, 0, 0, 0);
}

template<int LNUM, int S, int XOFF, int RSC, int RSN>
__device__ __forceinline__ void epilogue(
    const f32x4& ac0, const f32x4& ac1, const f32x4& ac2, int jt,
    float B1, float B2, float B3,
    uint16_t* __restrict__ Xh, uint16_t* __restrict__ Xn,
    float* __restrict__ outp, int t, int b0, int llo, int lhi)
{
  const int j = jt * 16 + llo;
  const bool valid = (j < S);
  #pragma unroll
  for (int r = 0; r < 4; ++r){
    const int row = lhi * 4 + r;
    float ff1 = tanh_f(ac0[r] + B1);
    float ff2 = tanh_f(ac1[r] + B2);
    float tt  = sigm_f(ac2[r] + B3);
    float h = ff1 + tt * (ff2 - ff1);
    if (valid){
      uint16_t hb = bfbits(h);
      Xh[row * RSC + XOFF + j] = hb;
      if constexpr (LNUM < 2)
        Xn[row * RSN + j] = hb;
      else
        outp[((size_t)(b0 + row) * T_ + t) * 128 + j] = h;
    }
  }
}

__global__ __launch_bounds__(1024, 4) void cfc_main(
    const float* __restrict__ elapsed, const float* __restrict__ enc,
    const float* __restrict__ b1_0, const float* __restrict__ b2_0,
    const float* __restrict__ ba0,  const float* __restrict__ bb0,
    const float* __restrict__ b1_1, const float* __restrict__ b2_1,
    const float* __restrict__ ba1,  const float* __restrict__ bb1,
    const float* __restrict__ b1_2, const float* __restrict__ b2_2,
    const float* __restrict__ ba2,  const float* __restrict__ bb2,
    const uint16_t* __restrict__ Wp, float* __restrict__ out)
{
  const int tid = threadIdx.x;
  const int wave = tid >> 6, lane = tid & 63;
  const int llo = lane & 15, lhi = lane >> 4;
  const int b0 = blockIdx.x * 16;

  // 96,768 B LDS -> 1 block/CU -> 16 waves = 4/SIMD -> 128-VGPR budget.
  __shared__ uint16_t X0[2 * 16 * RS0];
  __shared__ uint16_t X1[2 * 16 * RS1];
  __shared__ uint16_t X2[2 * 16 * RS2];
  __shared__ float    xl[T_ * 16];          // elapsed, transposed [t][row]

  for (int i = tid; i < 2 * 16 * RS0; i += 1024) X0[i] = 0;
  for (int i = tid; i < 2 * 16 * RS1; i += 1024) X1[i] = 0;
  for (int i = tid; i < 2 * 16 * RS2; i += 1024) X2[i] = 0;
  for (int i = tid; i < 16 * T_; i += 1024){
    int row = i >> 9, t = i & 511;
    xl[t * 16 + row] = elapsed[(size_t)(b0 + row) * T_ + t];
  }
  __syncthreads();

  for (int i = tid; i < 16 * 512; i += 1024){
    int row = i >> 9, c = i & 511;
    float v = enc[(size_t)(b0 + row) * 512 + c];
    uint16_t hb = bfbits(v);
    if (c < 231)       X0[row * RS0 + 1 + c] = hb;
    else if (c < 384)  X1[row * RS1 + c] = hb;
    else               X2[row * RS2 + (c - 231)] = hb;
  }

  // tile assignment
  const int jt0 = (wave < 15) ? wave : 14;    // wave 15 duplicates tile 14
  const int jt1 = (wave < 10) ? wave : 0;     // active: wave < 10
  const int jt2 = (wave >= 8) ? (wave - 8) : 0; // active: wave >= 8

  // biases -> registers
  float b0r[3], b1r[3], b2r[3];
  {
    const int j = jt0 * 16 + llo; const bool v = (j < 231);
    b0r[0] = v ? b1_0[j] : 0.f; b0r[1] = v ? b2_0[j] : 0.f; b0r[2] = v ? (ba0[j] + bb0[j]) : 0.f;
  }
  {
    const int j = jt1 * 16 + llo; const bool v = (wave < 10) && (j < 153);
    b1r[0] = v ? b1_1[j] : 0.f; b1r[1] = v ? b2_1[j] : 0.f; b1r[2] = v ? (ba1[j] + bb1[j]) : 0.f;
  }
  {
    const int j = jt2 * 16 + llo; const bool v = (wave >= 8) && (j < 128);
    b2r[0] = v ? b1_2[j] : 0.f; b2r[1] = v ? b2_2[j] : 0.f; b2r[2] = v ? (ba2[j] + bb2[j]) : 0.f;
  }

  // weight pointers (wave-uniform base + lane)
  const bf16x8* W0_8 = (const bf16x8*)(Wp);
  const bf16x8* W1_8 = (const bf16x8*)(Wp + 184320);
  const bf16x8* W2_8 = (const bf16x8*)(Wp + 368640);
  const bf16x8 *p0[3], *p1[3], *p2[3];
  #pragma unroll
  for (int m = 0; m < 3; ++m){
    p0[m] = W0_8 + (size_t)(m * 15 + jt0) * (8 * 64)  + lane;
    p1[m] = W1_8 + (size_t)(m * 10 + jt1) * (12 * 64) + lane;
    p2[m] = W2_8 + (size_t)(m * 8  + jt2) * (9 * 64)  + lane;
  }

  if (tid < 16) X0[tid * RS0] = bfbits(xl[tid]);
  __syncthreads();

  // prologue: first 2 L0 groups in flight (loop-carried)
  WG<8> g0a, g0b;
  wload<8>(p0[0], g0a);
  wload<8>(p0[1], g0b);

  int cur = 0;
  #pragma unroll 1
  for (int t = 0; t < T_; ++t){
    const int nxt = cur ^ 1;
    uint16_t* X0c = X0 + cur * 16 * RS0; uint16_t* X0n = X0 + nxt * 16 * RS0;
    uint16_t* X1c = X1 + cur * 16 * RS1; uint16_t* X1n = X1 + nxt * 16 * RS1;
    uint16_t* X2c = X2 + cur * 16 * RS2; uint16_t* X2n = X2 + nxt * 16 * RS2;

    WG<6> h0a;             // L1 m0-lo, prefetched at end of phase 1
    WG<9> k0, k1, k2;      // L2 groups (filled by phase 2 for waves >= 8)

    // ================= phase 1: layer 0 (all waves, 1 tile) =================
    {
      WG<8> g0c;
      wload<8>(p0[2], g0c);
      bf16x8 a0[8];
      const uint16_t* arow = X0c + llo * RS0 + lhi * 8;
      #pragma unroll
      for (int k = 0; k < 8; ++k) a0[k] = *(const bf16x8*)(arow + k * 32);

      f32x4 A0 = {0.f,0.f,0.f,0.f}, A1 = A0, A2 = A0;
      wmfma<8>(a0, g0a, A0);
      wmfma<8>(a0, g0b, A1);
      wmfma<8>(a0, g0c, A2);
      epilogue<0, 231, 1, RS0, RS1>(A0, A1, A2, jt0, b0r[0], b0r[1], b0r[2],
                                    X0n, X1c, out, t, b0, llo, lhi);
      if (wave < 10) wload<6>(p1[0], h0a);      // L1 prefetch, in flight over BAR
    }
    BAR();

    // ================= phase 2: layer 1 (waves 0-9); waves 10-15 prefetch L2 ==
    if (wave < 10){
      const uint16_t* brow = X1c + llo * RS1 + lhi * 8;
      WG<6> h1a, h2a, h0b, h1b, h2b;
      wload<6>(p1[1], h1a);
      bf16x8 aL[6];
      #pragma unroll
      for (int k = 0; k < 6; ++k) aL[k] = *(const bf16x8*)(brow + k * 32);
      f32x4 C0 = {0.f,0.f,0.f,0.f}, C1 = C0, C2 = C0;
      wmfma<6>(aL, h0a, C0); wload<6>(p1[2], h2a);
      wmfma<6>(aL, h1a, C1); wload<6>(p1[0] + 6*64, h0b);
      wmfma<6>(aL, h2a, C2); wload<6>(p1[1] + 6*64, h1b);
      bf16x8 aH[6];
      #pragma unroll
      for (int k = 0; k < 6; ++k) aH[k] = *(const bf16x8*)(brow + (k + 6) * 32);
      wmfma<6>(aH, h0b, C0); wload<6>(p1[2] + 6*64, h2b);
      wmfma<6>(aH, h1b, C1);
      if (wave >= 8) wload<9>(p2[0], k0);
      wmfma<6>(aH, h2b, C2);
      if (wave >= 8) wload<9>(p2[1], k1);
      epilogue<1, 153, 231, RS1, RS2>(C0, C1, C2, jt1, b1r[0], b1r[1], b1r[2],
                                      X1n, X2c, out, t, b0, llo, lhi);
      if (wave >= 8) wload<9>(p2[2], k2);
    } else {
      wload<9>(p2[0], k0);
      wload<9>(p2[1], k1);
      wload<9>(p2[2], k2);
    }
    BAR();

    // ================= phase 3: layer 2 (waves 8-15); waves 0-7 prefetch L0 ==
    if (wave >= 8){
      bf16x8 a2[9];
      const uint16_t* crow = X2c + llo * RS2 + lhi * 8;
      #pragma unroll
      for (int k = 0; k < 9; ++k) a2[k] = *(const bf16x8*)(crow + k * 32);
      f32x4 E0 = {0.f,0.f,0.f,0.f}, E1 = E0, E2 = E0;
      wmfma<9>(a2, k0, E0); wload<8>(p0[0], g0a);   // prefetch t+1 L0
      wmfma<9>(a2, k1, E1); wload<8>(p0[1], g0b);
      wmfma<9>(a2, k2, E2);
      epilogue<2, 128, 153, RS2, RS2>(E0, E1, E2, jt2, b2r[0], b2r[1], b2r[2],
                                      X2n, nullptr, out, t, b0, llo, lhi);
    } else {
      wload<8>(p0[0], g0a);
      wload<8>(p0[1], g0b);
    }
    if (tid < 16 && t + 1 < T_)
      X0n[tid * RS0] = bfbits(xl[(t + 1) * 16 + tid]);
    BAR();
    cur = nxt;
  }

  // rnn_hidden = concat(h0,h1,h2); after 512 steps final state is in buffer 0
  const size_t OH = (size_t)B_ * T_ * 128;
  for (int i = tid; i < 16 * 512; i += 1024){
    int row = i >> 9, c = i & 511;
    float v;
    if (c < 231)      v = bf2f(X0[row * RS0 + 1 + c]);
    else if (c < 384) v = bf2f(X1[row * RS1 + c]);
    else              v = bf2f(X2[row * RS2 + (c - 231)]);
    out[OH + (size_t)(b0 + row) * 512 + c] = v;
  }
}

extern "C" void kernel_launch(void* const* d_in, const int* in_sizes, int n_in,
                              void* d_out, int out_size, void* d_ws, size_t ws_size,
                              hipStream_t stream)
{
  const float* elapsed = (const float*)d_in[0];
  const float* enc     = (const float*)d_in[1];
  const float* W1_0 = (const float*)d_in[2];  const float* b1_0 = (const float*)d_in[3];
  const float* W2_0 = (const float*)d_in[4];  const float* b2_0 = (const float*)d_in[5];
  const float* Wa0  = (const float*)d_in[6];  const float* ba0  = (const float*)d_in[7];
  const float* Wb0  = (const float*)d_in[8];  const float* bb0  = (const float*)d_in[9];
  const float* M0   = (const float*)d_in[10];
  const float* W1_1 = (const float*)d_in[11]; const float* b1_1 = (const float*)d_in[12];
  const float* W2_1 = (const float*)d_in[13]; const float* b2_1 = (const float*)d_in[14];
  const float* Wa1  = (const float*)d_in[15]; const float* ba1  = (const float*)d_in[16];
  const float* Wb1  = (const float*)d_in[17]; const float* bb1  = (const float*)d_in[18];
  const float* M1   = (const float*)d_in[19];
  const float* W1_2 = (const float*)d_in[20]; const float* b1_2 = (const float*)d_in[21];
  const float* W2_2 = (const float*)d_in[22]; const float* b2_2 = (const float*)d_in[23];
  const float* Wa2  = (const float*)d_in[24]; const float* ba2  = (const float*)d_in[25];
  const float* Wb2  = (const float*)d_in[26]; const float* bb2  = (const float*)d_in[27];
  const float* M2   = (const float*)d_in[28];

  uint16_t* wp = (uint16_t*)d_ws;

  pack_w<<<90, 256, 0, stream>>>(W1_0, W2_0, Wa0, Wb0, M0, wp,          15,  8, 231, 232);
  pack_w<<<90, 256, 0, stream>>>(W1_1, W2_1, Wa1, Wb1, M1, wp + 184320, 10, 12, 153, 384);
  pack_w<<<54, 256, 0, stream>>>(W1_2, W2_2, Wa2, Wb2, M2, wp + 368640,  8,  9, 128, 281);

  cfc_main<<<32, 1024, 0, stream>>>(elapsed, enc,
                                    b1_0, b2_0, ba0, bb0,
                                    b1_1, b2_1, ba1, bb1,
                                    b1_2, b2_2, ba2, bb2,
                                    wp, (float*)d_out);
}

// Round 6
// 11663.519 us; speedup vs baseline: 1.6245x; 1.6245x over previous
//
#include <hip/hip_runtime.h>
#include <stdint.h>

#define B_ 512
#define T_ 512

typedef __attribute__((ext_vector_type(8))) __bf16 bf16x8;
typedef __attribute__((ext_vector_type(4))) float f32x4;
typedef __attribute__((ext_vector_type(8))) unsigned short u16x8;

// d_ws layout (bytes):
//   [0)            packed bf16 weights, 958464 u16 = 1916928 B (as R1-5 pack_w)
//   [N0OFF)        n0 rings: 32 groups x 4 slots x 16 rows x 240 cols u16 = 983040 B
//   [N1OFF)        n1 rings: 32 groups x 4 slots x 16 rows x 160 cols u16 = 655360 B
//   [FLOFF)        flags: 32 groups x 5 counters x 16 ints (64B spaced) = 10240 B
#define N0OFF 1916928u
#define N1OFF 2899968u
#define FLOFF 3555328u

// Pipeline: per batch-group g (16 rows), 5 stage blocks on one XCD:
//   SID 0: L0 tiles 0-7    SID 1: L0 tiles 8-14
//   SID 2: L1 tiles 0-4    SID 3: L1 tiles 5-9
//   SID 4: L2 tiles 0-7
// Weights live in REGISTERS for the whole 512-step loop. States flow through
// depth-4 rings with monotonic progress counters (prog = completed_step + 2;
// init state -1 => prog 1).

static __device__ __forceinline__ uint16_t bfbits(float f){
  __bf16 h = (__bf16)f; return __builtin_bit_cast(uint16_t, h);
}
static __device__ __forceinline__ float sigm_f(float x){
  return __builtin_amdgcn_rcpf(1.0f + __builtin_amdgcn_exp2f(-1.4426950408889634f*x));
}
static __device__ __forceinline__ float tanh_f(float x){
  return 2.0f*__builtin_amdgcn_rcpf(1.0f + __builtin_amdgcn_exp2f(-2.8853900817779268f*x)) - 1.0f;
}
static __device__ __forceinline__ uint32_t ldg32(const uint32_t* p){
  return __hip_atomic_load(p, __ATOMIC_RELAXED, __HIP_MEMORY_SCOPE_AGENT);
}
static __device__ __forceinline__ uint16_t ldg16(const uint16_t* p){
  return __hip_atomic_load(p, __ATOMIC_RELAXED, __HIP_MEMORY_SCOPE_AGENT);
}
static __device__ __forceinline__ void waitge(int* f, int idx, int val){
  while (__hip_atomic_load(&f[idx*16], __ATOMIC_ACQUIRE, __HIP_MEMORY_SCOPE_AGENT) < val)
    __builtin_amdgcn_s_sleep(1);
}

__global__ void zero_flags(uint8_t* wsb){
  int i = blockIdx.x*256 + threadIdx.x;
  if (i < 2560) ((int*)(wsb + FLOFF))[i] = 0;
}

__global__ void pack_w(const float* __restrict__ W1, const float* __restrict__ W2,
                       const float* __restrict__ Wa, const float* __restrict__ Wb,
                       const float* __restrict__ Msk, uint16_t* __restrict__ dst,
                       int NPT, int KT, int S, int C)
{
  int c = blockIdx.x * 256 + threadIdx.x;
  int chunks = 3 * NPT * KT * 64;
  if (c >= chunks) return;
  int perN = KT * 64;
  int n3 = c / perN, r = c % perN;
  int kt = r >> 6, lane = r & 63;
  int m = n3 / NPT, nt = n3 % NPT;
  int j = nt * 16 + (lane & 15);
  int kb = kt * 32 + (lane >> 4) * 8;
  u16x8 o;
  #pragma unroll
  for (int i = 0; i < 8; ++i){
    int k = kb + i;
    float v = 0.f;
    if (j < S && k < C){
      size_t idx = (size_t)j * C + k;
      if (m == 0)      v = W1[idx] * Msk[idx];
      else if (m == 1) v = W2[idx] * Msk[idx];
      else             v = Wa[idx] + Wb[idx];
    }
    o[i] = bfbits(v);
  }
  *(u16x8*)(dst + (size_t)c * 8) = o;
}

template<int SID>
__device__ __forceinline__ void stage_run(
    int g, int tid,
    const float* __restrict__ elapsed, const float* __restrict__ enc,
    const float* __restrict__ bp1, const float* __restrict__ bp2,
    const float* __restrict__ bpa, const float* __restrict__ bpb,
    const uint16_t* __restrict__ Wp, uint8_t* __restrict__ wsb,
    float* __restrict__ out, uint16_t* XA, float* xl)
{
  constexpr int LAYER = (SID<2)?0:((SID<4)?1:2);
  constexpr int NPTF  = (LAYER==0)?15:((LAYER==1)?10:8);
  constexpr int KT    = (LAYER==0)?8:((LAYER==1)?12:9);
  constexpr int T0    = (SID==0)?0:((SID==1)?8:((SID==2)?0:((SID==3)?5:0)));
  constexpr int NT    = (SID==0)?8:((SID==1)?7:((SID==2)?5:((SID==3)?5:8)));
  constexpr int SCOL  = (LAYER==0)?231:((LAYER==1)?153:128);
  constexpr int RS    = (LAYER==0)?264:((LAYER==1)?392:296);
  constexpr int CBASE = (LAYER==0)?0:((LAYER==1)?231:384);
  constexpr size_t WOFF = (LAYER==0)?0:((LAYER==1)?184320:368640);

  const int wave = tid>>6, lane = tid&63, llo = lane&15, lhi = lane>>4;
  const int rowg = tid>>4, cg = tid&15;
  const int b0 = g*16;

  uint16_t* N0 = (uint16_t*)(wsb + N0OFF) + (size_t)g*(4*16*240);
  uint16_t* N1 = (uint16_t*)(wsb + N1OFF) + (size_t)g*(4*16*160);
  int* FLG = (int*)(wsb + FLOFF) + g*80;

  // tile assignment within this stage block (wave-uniform)
  const int i2v = 2*wave + 1;
  const bool has2 = (i2v < NT);
  const int t1 = T0 + ((2*wave < NT) ? 2*wave : NT-1);   // dup last tile if short
  const int t2 = T0 + (has2 ? i2v : 0);

  // ---- persistent weights -> registers (loaded once) ----
  bf16x8 w1r[3][KT], w2r[3][KT];
  {
    const bf16x8* W8 = (const bf16x8*)(Wp + WOFF);
    #pragma unroll
    for (int m = 0; m < 3; ++m){
      #pragma unroll
      for (int kt = 0; kt < KT; ++kt){
        w1r[m][kt] = W8[(size_t)((m*NPTF + t1)*KT + kt)*64 + lane];
        w2r[m][kt] = W8[(size_t)((m*NPTF + t2)*KT + kt)*64 + lane];
      }
    }
  }
  // ---- biases -> registers ----
  float bs1[3], bs2[3];
  {
    int j = t1*16 + llo; bool v = (j < SCOL);
    bs1[0] = v ? bp1[j] : 0.f; bs1[1] = v ? bp2[j] : 0.f;
    bs1[2] = v ? (bpa[j] + bpb[j]) : 0.f;
    j = t2*16 + llo; v = has2 && (j < SCOL);
    int js = (j < SCOL) ? j : 0;
    bs2[0] = v ? bp1[js] : 0.f; bs2[1] = v ? bp2[js] : 0.f;
    bs2[2] = v ? (bpa[js] + bpb[js]) : 0.f;
  }

  // ---- init LDS ----
  for (int i = tid; i < 16*RS; i += 256) XA[i] = 0;   // pads must be 0 (NaN guard)
  if constexpr (SID < 2){
    for (int i = tid; i < 16*512; i += 256){
      int row = i >> 9, tt = i & 511;
      xl[tt*16 + row] = elapsed[(size_t)(b0 + row)*T_ + tt];
    }
  }
  // ---- init state (-1) into ring slot 3 / LDS ----
  if constexpr (SID == 0){
    for (int i = tid; i < 16*128; i += 256){
      int row = i >> 7, j = i & 127;
      N0[(size_t)(3*16 + row)*240 + j] = bfbits(enc[(size_t)(b0+row)*512 + j]);
    }
  } else if constexpr (SID == 1){
    for (int i = tid; i < 16*112; i += 256){
      int row = i / 112, j = 128 + i % 112;
      N0[(size_t)(3*16 + row)*240 + j] = (j < 231) ? bfbits(enc[(size_t)(b0+row)*512 + j]) : (uint16_t)0;
    }
  } else if constexpr (SID == 2){
    for (int i = tid; i < 16*80; i += 256){
      int row = i / 80, j = i % 80;
      N1[(size_t)(3*16 + row)*160 + j] = bfbits(enc[(size_t)(b0+row)*512 + 231 + j]);
    }
  } else if constexpr (SID == 3){
    for (int i = tid; i < 16*80; i += 256){
      int row = i / 80, j = 80 + i % 80;
      N1[(size_t)(3*16 + row)*160 + j] = (j < 153) ? bfbits(enc[(size_t)(b0+row)*512 + 231 + j]) : (uint16_t)0;
    }
  } else {
    for (int i = tid; i < 16*128; i += 256){
      int row = i >> 7, j = i & 127;
      XA[row*RS + 153 + j] = bfbits(enc[(size_t)(b0+row)*512 + 384 + j]);
    }
  }
  __threadfence();
  __syncthreads();
  if (tid == 0)
    __hip_atomic_store(&FLG[SID*16], 1, __ATOMIC_RELEASE, __HIP_MEMORY_SCOPE_AGENT);

  const size_t OH = (size_t)B_ * T_ * 128;

  #pragma unroll 1
  for (int t = 0; t < T_; ++t){
    // ---- wait for inputs + backpressure ----
    if (tid == 0){
      if constexpr (SID == 0){ waitge(FLG,1,t+1); waitge(FLG,2,t-2); waitge(FLG,3,t-2); }
      else if constexpr (SID == 1){ waitge(FLG,0,t+1); waitge(FLG,2,t-2); waitge(FLG,3,t-2); }
      else if constexpr (SID == 2){ waitge(FLG,0,t+2); waitge(FLG,1,t+2); waitge(FLG,3,t+1); waitge(FLG,4,t-2); }
      else if constexpr (SID == 3){ waitge(FLG,0,t+2); waitge(FLG,1,t+2); waitge(FLG,2,t+1); waitge(FLG,4,t-2); }
      else                        { waitge(FLG,2,t+2); waitge(FLG,3,t+2); }
    }
    __syncthreads();

    // ---- stage A-matrix into LDS (agent-scope loads: XCD-L2 safe) ----
    if constexpr (SID < 2){
      const uint16_t* src = N0 + (size_t)((((t+3)&3)*16) + rowg)*240;   // h0(t-1)
      const uint32_t* s32 = (const uint32_t*)src;
      uint16_t* dst = XA + rowg*RS;
      for (int pc = cg; pc < 115; pc += 16){
        uint32_t v = ldg32(s32 + pc);
        dst[1 + 2*pc] = (uint16_t)v;
        dst[2 + 2*pc] = (uint16_t)(v >> 16);
      }
      if (cg == 0){
        dst[231] = ldg16(src + 230);
        dst[0]   = bfbits(xl[t*16 + rowg]);       // x_t
      }
    } else if constexpr (SID < 4){
      const uint16_t* s0 = N0 + (size_t)(((t&3)*16) + rowg)*240;        // n0(t)
      const uint32_t* s032 = (const uint32_t*)s0;
      uint16_t* dst = XA + rowg*RS;
      for (int pc = cg; pc < 115; pc += 16)
        *(uint32_t*)(dst + 2*pc) = ldg32(s032 + pc);
      const uint16_t* s1 = N1 + (size_t)((((t+3)&3)*16) + rowg)*160;    // h1(t-1)
      const uint32_t* s132 = (const uint32_t*)s1;
      for (int jc = cg; jc < 76; jc += 16){
        uint32_t v = ldg32(s132 + jc);
        dst[231 + 2*jc] = (uint16_t)v;
        dst[232 + 2*jc] = (uint16_t)(v >> 16);
      }
      if (cg == 0){
        dst[230] = ldg16(s0 + 230);
        dst[383] = ldg16(s1 + 152);
      }
    } else {
      const uint16_t* s1 = N1 + (size_t)(((t&3)*16) + rowg)*160;        // n1(t)
      const uint32_t* s132 = (const uint32_t*)s1;
      uint16_t* dst = XA + rowg*RS;
      for (int jc = cg; jc < 76; jc += 16)
        *(uint32_t*)(dst + 2*jc) = ldg32(s132 + jc);
      if (cg == 0) dst[152] = ldg16(s1 + 152);
      // cols 153..280 = h2(t-1), persistent in LDS from previous epilogue
    }
    __syncthreads();

    // ---- A fragments ----
    bf16x8 a[KT];
    {
      const uint16_t* ar = XA + llo*RS + lhi*8;
      #pragma unroll
      for (int kt = 0; kt < KT; ++kt) a[kt] = *(const bf16x8*)(ar + kt*32);
    }
    if constexpr (SID == 4) __syncthreads();   // WAR: epilogue writes h2 into XA

    // ---- compute + epilogue ----
    auto comp = [&](const bf16x8 (&w)[3][KT], int jt, const float* bs){
      f32x4 c0 = {0.f,0.f,0.f,0.f}, c1 = c0, c2 = c0;
      #pragma unroll
      for (int kt = 0; kt < KT; ++kt){
        c0 = __builtin_amdgcn_mfma_f32_16x16x32_bf16(a[kt], w[0][kt], c0, 0, 0, 0);
        c1 = __builtin_amdgcn_mfma_f32_16x16x32_bf16(a[kt], w[1][kt], c1, 0, 0, 0);
        c2 = __builtin_amdgcn_mfma_f32_16x16x32_bf16(a[kt], w[2][kt], c2, 0, 0, 0);
      }
      const int j = jt*16 + llo;
      #pragma unroll
      for (int r = 0; r < 4; ++r){
        const int row = lhi*4 + r;
        float ff1 = tanh_f(c0[r] + bs[0]);
        float ff2 = tanh_f(c1[r] + bs[1]);
        float tt  = sigm_f(c2[r] + bs[2]);
        float h = ff1 + tt*(ff2 - ff1);
        uint16_t hb = bfbits(h);
        if constexpr (SID < 2)
          N0[(size_t)(((t&3)*16) + row)*240 + j] = hb;    // j<240; zeros land in pad
        else if constexpr (SID < 4)
          N1[(size_t)(((t&3)*16) + row)*160 + j] = hb;
        else {
          XA[row*RS + 153 + j] = hb;                      // h2 persists in LDS
          out[((size_t)(b0+row)*T_ + t)*128 + j] = h;     // rnn_out
        }
        if (t == T_-1 && j < SCOL)
          out[OH + (size_t)(b0+row)*512 + CBASE + j] = h; // rnn_hidden
      }
    };
    comp(w1r, t1, bs1);
    if (has2) comp(w2r, t2, bs2);

    __threadfence();           // release own ring writes device-wide
    __syncthreads();
    if (tid == 0)
      __hip_atomic_store(&FLG[SID*16], t+2, __ATOMIC_RELEASE, __HIP_MEMORY_SCOPE_AGENT);
  }
}

__global__ __launch_bounds__(256, 1) void cfc_pipe(
    const float* __restrict__ elapsed, const float* __restrict__ enc,
    const float* __restrict__ b1_0, const float* __restrict__ b2_0,
    const float* __restrict__ ba0,  const float* __restrict__ bb0,
    const float* __restrict__ b1_1, const float* __restrict__ b2_1,
    const float* __restrict__ ba1,  const float* __restrict__ bb1,
    const float* __restrict__ b1_2, const float* __restrict__ b2_2,
    const float* __restrict__ ba2,  const float* __restrict__ bb2,
    const uint16_t* __restrict__ Wp, uint8_t* __restrict__ wsb,
    float* __restrict__ out)
{
  __shared__ uint16_t XA[16*392];      // 12544 B (max stage stride)
  __shared__ float    xl[16*512];      // 32768 B (elapsed slice, S0 only)
  __shared__ float    lds_pad[10200];  // 40800 B -> total 86112 B -> 1 block/CU
  if (elapsed == nullptr) lds_pad[0] = 1.f;   // keep allocated (never true)

  const int bid = blockIdx.x;
  const int xcd = bid & 7, k = bid >> 3;      // group's 5 stages share an XCD
  const int g = xcd + 8*(k/5);
  const int s = k - 5*(k/5);
  const int tid = threadIdx.x;

  switch (s){
    case 0: stage_run<0>(g, tid, elapsed, enc, b1_0, b2_0, ba0, bb0, Wp, wsb, out, XA, xl); break;
    case 1: stage_run<1>(g, tid, elapsed, enc, b1_0, b2_0, ba0, bb0, Wp, wsb, out, XA, xl); break;
    case 2: stage_run<2>(g, tid, elapsed, enc, b1_1, b2_1, ba1, bb1, Wp, wsb, out, XA, xl); break;
    case 3: stage_run<3>(g, tid, elapsed, enc, b1_1, b2_1, ba1, bb1, Wp, wsb, out, XA, xl); break;
    default: stage_run<4>(g, tid, elapsed, enc, b1_2, b2_2, ba2, bb2, Wp, wsb, out, XA, xl); break;
  }
}

extern "C" void kernel_launch(void* const* d_in, const int* in_sizes, int n_in,
                              void* d_out, int out_size, void* d_ws, size_t ws_size,
                              hipStream_t stream)
{
  const float* elapsed = (const float*)d_in[0];
  const float* enc     = (const float*)d_in[1];
  const float* W1_0 = (const float*)d_in[2];  const float* b1_0 = (const float*)d_in[3];
  const float* W2_0 = (const float*)d_in[4];  const float* b2_0 = (const float*)d_in[5];
  const float* Wa0  = (const float*)d_in[6];  const float* ba0  = (const float*)d_in[7];
  const float* Wb0  = (const float*)d_in[8];  const float* bb0  = (const float*)d_in[9];
  const float* M0   = (const float*)d_in[10];
  const float* W1_1 = (const float*)d_in[11]; const float* b1_1 = (const float*)d_in[12];
  const float* W2_1 = (const float*)d_in[13]; const float* b2_1 = (const float*)d_in[14];
  const float* Wa1  = (const float*)d_in[15]; const float* ba1  = (const float*)d_in[16];
  const float* Wb1  = (const float*)d_in[17]; const float* bb1  = (const float*)d_in[18];
  const float* M1   = (const float*)d_in[19];
  const float* W1_2 = (const float*)d_in[20]; const float* b1_2 = (const float*)d_in[21];
  const float* W2_2 = (const float*)d_in[22]; const float* b2_2 = (const float*)d_in[23];
  const float* Wa2  = (const float*)d_in[24]; const float* ba2  = (const float*)d_in[25];
  const float* Wb2  = (const float*)d_in[26]; const float* bb2  = (const float*)d_in[27];
  const float* M2   = (const float*)d_in[28];

  uint8_t*  wsb = (uint8_t*)d_ws;
  uint16_t* wp  = (uint16_t*)d_ws;

  zero_flags<<<10, 256, 0, stream>>>(wsb);
  pack_w<<<90, 256, 0, stream>>>(W1_0, W2_0, Wa0, Wb0, M0, wp,          15,  8, 231, 232);
  pack_w<<<90, 256, 0, stream>>>(W1_1, W2_1, Wa1, Wb1, M1, wp + 184320, 10, 12, 153, 384);
  pack_w<<<54, 256, 0, stream>>>(W1_2, W2_2, Wa2, Wb2, M2, wp + 368640,  8,  9, 128, 281);

  cfc_pipe<<<160, 256, 0, stream>>>(elapsed, enc,
                                    b1_0, b2_0, ba0, bb0,
                                    b1_1, b2_1, ba1, bb1,
                                    b1_2, b2_2, ba2, bb2,
                                    wp, wsb, (float*)d_out);
}

// Round 8
// 5159.863 us; speedup vs baseline: 3.6720x; 2.2604x over previous
//
#include <hip/hip_runtime.h>
#include <stdint.h>

#define B_ 512
#define T_ 512

typedef __attribute__((ext_vector_type(8))) __bf16 bf16x8;
typedef __attribute__((ext_vector_type(4))) float f32x4;
typedef __attribute__((ext_vector_type(8))) unsigned short u16x8;

// d_ws layout (bytes):
//   [0)        packed bf16 weights (pack_w), 958464 u16 = 1916928 B
//   [N0OFF)    R0 ring: 16 groups x 4 slots x 32 rows x 240 cols u16 = 983040 B
//   [N1OFF)    R1 ring: 16 x 4 x 32 x 160 u16 = 655360 B
//   [N2OFF)    R2 ring: 16 x 4 x 32 x 128 u16 = 524288 B
//   [FLOFF)    flags: 16 groups x 9 stages x 16 ints (64B spaced) = 9216 B
#define N0OFF 1916928u
#define N1OFF 2899968u
#define N2OFF 3555328u
#define FLOFF 4079616u

// 9 stages per 32-row group: S0-2 = L0 tiles {0-4,5-9,10-14}; S3-6 = L1 tiles
// {0-2,3-5,6-7,8-9}; S7-8 = L2 tiles {0-3,4-7}. Weights live in LDS (loaded
// once). States flow through depth-4 rings; flag = completed step + 2.
constexpr int L_[9]   = {0,0,0, 1,1,1,1, 2,2};
constexpr int NT0_[9] = {0,5,10, 0,3,6,8, 0,4};
constexpr int NT_[9]  = {5,5,5, 3,3,2,2, 4,4};
constexpr int KT_[3]  = {8,12,9};
constexpr int NPT_[3] = {15,10,8};
constexpr int SC_[3]  = {231,153,128};
constexpr int RS_[3]  = {264,392,296};
constexpr int CB_[3]  = {0,231,384};
constexpr int RC_[3]  = {240,160,128};
constexpr unsigned WOFF_[3] = {0u,184320u,368640u};
// wait lists: flag index (stage within group) + lag (need flag >= t+lag)
constexpr int WN_[9] = {6,6,6, 8,8,8,8, 5,5};
constexpr int WF_[9][8] = {
  {1,2,3,4,5,6,0,0},{0,2,3,4,5,6,0,0},{0,1,3,4,5,6,0,0},
  {0,1,2,4,5,6,7,8},{0,1,2,3,5,6,7,8},{0,1,2,3,4,6,7,8},{0,1,2,3,4,5,7,8},
  {3,4,5,6,8,0,0,0},{3,4,5,6,7,0,0,0}};
constexpr int WL_[9][8] = {
  {1,1,-2,-2,-2,-2,0,0},{1,1,-2,-2,-2,-2,0,0},{1,1,-2,-2,-2,-2,0,0},
  {2,2,2,1,1,1,-2,-2},{2,2,2,1,1,1,-2,-2},{2,2,2,1,1,1,-2,-2},{2,2,2,1,1,1,-2,-2},
  {2,2,2,2,1,0,0,0},{2,2,2,2,1,0,0,0}};

static __device__ __forceinline__ uint16_t bfbits(float f){
  __bf16 h = (__bf16)f; return __builtin_bit_cast(uint16_t, h);
}
static __device__ __forceinline__ float sigm_f(float x){
  return __builtin_amdgcn_rcpf(1.0f + __builtin_amdgcn_exp2f(-1.4426950408889634f*x));
}
static __device__ __forceinline__ float tanh_f(float x){
  return 2.0f*__builtin_amdgcn_rcpf(1.0f + __builtin_amdgcn_exp2f(-2.8853900817779268f*x)) - 1.0f;
}
static __device__ __forceinline__ uint32_t ldg32(const uint32_t* p){
  return __hip_atomic_load(p, __ATOMIC_RELAXED, __HIP_MEMORY_SCOPE_AGENT);
}
static __device__ __forceinline__ uint16_t ldg16(const uint16_t* p){
  return __hip_atomic_load(p, __ATOMIC_RELAXED, __HIP_MEMORY_SCOPE_AGENT);
}
#define DRAIN() asm volatile("s_waitcnt vmcnt(0)" ::: "memory")

__global__ void zero_flags(uint8_t* wsb){
  int i = blockIdx.x*512 + threadIdx.x;
  if (i < 2304) ((int*)(wsb + FLOFF))[i] = 0;
}

__global__ void pack_w(const float* __restrict__ W1, const float* __restrict__ W2,
                       const float* __restrict__ Wa, const float* __restrict__ Wb,
                       const float* __restrict__ Msk, uint16_t* __restrict__ dst,
                       int NPT, int KT, int S, int C)
{
  int c = blockIdx.x * 256 + threadIdx.x;
  int chunks = 3 * NPT * KT * 64;
  if (c >= chunks) return;
  int perN = KT * 64;
  int n3 = c / perN, r = c % perN;
  int kt = r >> 6, lane = r & 63;
  int m = n3 / NPT, nt = n3 % NPT;
  int j = nt * 16 + (lane & 15);
  int kb = kt * 32 + (lane >> 4) * 8;
  u16x8 o;
  #pragma unroll
  for (int i = 0; i < 8; ++i){
    int k = kb + i;
    float v = 0.f;
    if (j < S && k < C){
      size_t idx = (size_t)j * C + k;
      if (m == 0)      v = W1[idx] * Msk[idx];
      else if (m == 1) v = W2[idx] * Msk[idx];
      else             v = Wa[idx] + Wb[idx];
    }
    o[i] = bfbits(v);
  }
  *(u16x8*)(dst + (size_t)c * 8) = o;
}

template<int SID>
__device__ __forceinline__ void stage_run(
    int g, int tid,
    const float* __restrict__ elapsed, const float* __restrict__ enc,
    const float* __restrict__ bp1, const float* __restrict__ bp2,
    const float* __restrict__ bpa, const float* __restrict__ bpb,
    const uint16_t* __restrict__ Wp, uint8_t* __restrict__ wsb,
    float* __restrict__ out, uint16_t* Wl, uint16_t* XA)
{
  constexpr int LAYER = L_[SID];
  constexpr int NT0 = NT0_[SID], NT = NT_[SID];
  constexpr int KT = KT_[LAYER], NPT = NPT_[LAYER];
  constexpr int SCOL = SC_[LAYER], RS = RS_[LAYER];
  constexpr int CBASE = CB_[LAYER], RC = RC_[LAYER];

  const int wave = tid >> 6, lane = tid & 63, llo = lane & 15, lhi = lane >> 4;
  const int rowg = tid >> 4, cg = tid & 15;       // 32 rows x 16 threads
  const int b0 = g * 32;

  uint16_t* R0 = (uint16_t*)(wsb + N0OFF) + (size_t)g * (4*32*240);
  uint16_t* R1 = (uint16_t*)(wsb + N1OFF) + (size_t)g * (4*32*160);
  uint16_t* R2 = (uint16_t*)(wsb + N2OFF) + (size_t)g * (4*32*128);
  int* FLG = (int*)(wsb + FLOFF) + g * (9*16);
  uint16_t* RNG = (LAYER==0) ? R0 : (LAYER==1) ? R1 : R2;

  // ---- weights: global (packed) -> LDS, once ----
  {
    const u16x8* Wp8 = (const u16x8*)(Wp + WOFF_[LAYER]);
    u16x8* Wl8 = (u16x8*)Wl;
    constexpr int CHUNKS = 3 * NT * KT * 64;
    for (int c = tid; c < CHUNKS; c += 512){
      int m = c / (NT*KT*64), r = c - m*(NT*KT*64);
      int tl = r / (KT*64),  r2 = r - tl*(KT*64);
      Wl8[c] = Wp8[(size_t)((m*NPT + NT0 + tl)*KT*64) + r2];
    }
  }
  // ---- XA zero (K-pad columns must stay 0) ----
  for (int i = tid; i < 32*RS; i += 512) XA[i] = 0;

  // ---- biases -> registers (wave owns tile NT0+wave) ----
  float bs0 = 0.f, bs1 = 0.f, bs2 = 0.f;
  if (wave < NT){
    const int j = (NT0 + wave)*16 + llo;
    if (j < SCOL){ bs0 = bp1[j]; bs1 = bp2[j]; bs2 = bpa[j] + bpb[j]; }
  }

  // ---- init own h-slice (state -1) into ring slot 3 ----
  for (int idx = tid; idx < 32*NT*16; idx += 512){
    int row = idx / (NT*16), jl = idx % (NT*16);
    int j = NT0*16 + jl;
    float v = 0.f;
    if (j < SCOL){
      if constexpr (LAYER == 0) v = enc[(size_t)(b0+row)*512 + j];
      else if constexpr (LAYER == 1) v = enc[(size_t)(b0+row)*512 + 231 + j];
      else v = enc[(size_t)(b0+row)*512 + 384 + j];
    }
    RNG[(size_t)(3*32 + row)*RC + j] = bfbits(v);
  }
  DRAIN();
  __syncthreads();
  if (tid == 0){
    __threadfence();
    __hip_atomic_store(&FLG[SID*16], 1, __ATOMIC_RELEASE, __HIP_MEMORY_SCOPE_AGENT);
  }

  const size_t OH = (size_t)B_ * T_ * 128;

  #pragma unroll 1
  for (int t = 0; t < T_; ++t){
    // ---- wait: batched relaxed polls, then one acquire (ordering inv) ----
    if (tid == 0){
      int spin = 0;
      for (;;){
        bool ok = true;
        #pragma unroll
        for (int i = 0; i < WN_[SID]; ++i){
          int v = __hip_atomic_load(&FLG[WF_[SID][i]*16], __ATOMIC_RELAXED,
                                    __HIP_MEMORY_SCOPE_AGENT);
          ok &= (v >= t + WL_[SID][i]);
        }
        if (ok) break;
        __builtin_amdgcn_s_sleep(2);
        if ((++spin & 15) == 0)   // staleness guard: periodic acquire
          (void)__hip_atomic_load(&FLG[WF_[SID][0]*16], __ATOMIC_ACQUIRE,
                                  __HIP_MEMORY_SCOPE_AGENT);
      }
      (void)__hip_atomic_load(&FLG[SID*16], __ATOMIC_ACQUIRE,
                              __HIP_MEMORY_SCOPE_AGENT);
    }
    __syncthreads();

    // ---- stage A-matrix into XA (sc1 ring loads read LLC: fence-free fresh) ----
    {
      uint16_t* dst = XA + rowg * RS;
      if constexpr (LAYER == 0){
        const uint16_t* src = R0 + (size_t)((((t+3)&3)*32) + rowg)*240;  // h0(t-1)
        const uint32_t* s32 = (const uint32_t*)src;
        for (int pc = cg; pc < 115; pc += 16){
          uint32_t v = ldg32(s32 + pc);
          dst[1 + 2*pc] = (uint16_t)v;
          dst[2 + 2*pc] = (uint16_t)(v >> 16);
        }
        if (cg == 0){
          dst[231] = ldg16(src + 230);
          dst[0] = bfbits(elapsed[(size_t)(b0 + rowg)*T_ + t]);          // x_t
        }
      } else if constexpr (LAYER == 1){
        const uint16_t* s0 = R0 + (size_t)(((t&3)*32) + rowg)*240;       // n0(t)
        const uint32_t* s032 = (const uint32_t*)s0;
        for (int pc = cg; pc < 115; pc += 16)
          *(uint32_t*)(dst + 2*pc) = ldg32(s032 + pc);
        const uint16_t* s1 = R1 + (size_t)((((t+3)&3)*32) + rowg)*160;   // h1(t-1)
        const uint32_t* s132 = (const uint32_t*)s1;
        for (int jc = cg; jc < 76; jc += 16){
          uint32_t v = ldg32(s132 + jc);
          dst[231 + 2*jc] = (uint16_t)v;
          dst[232 + 2*jc] = (uint16_t)(v >> 16);
        }
        if (cg == 0){
          dst[230] = ldg16(s0 + 230);
          dst[383] = ldg16(s1 + 152);
        }
      } else {
        const uint16_t* s1 = R1 + (size_t)(((t&3)*32) + rowg)*160;       // n1(t)
        const uint32_t* s132 = (const uint32_t*)s1;
        for (int jc = cg; jc < 76; jc += 16)
          *(uint32_t*)(dst + 2*jc) = ldg32(s132 + jc);
        const uint16_t* s2 = R2 + (size_t)((((t+3)&3)*32) + rowg)*128;   // h2(t-1)
        const uint32_t* s232 = (const uint32_t*)s2;
        for (int jc = cg; jc < 64; jc += 16){
          uint32_t v = ldg32(s232 + jc);
          dst[153 + 2*jc] = (uint16_t)v;
          dst[154 + 2*jc] = (uint16_t)(v >> 16);
        }
        if (cg == 0) dst[152] = ldg16(s1 + 152);
      }
    }
    __syncthreads();

    // ---- compute: wave owns tile NT0+wave (weights from LDS) ----
    if (wave < NT){
      const int nt = NT0 + wave;
      bf16x8 aL[KT], aH[KT];
      const uint16_t* ar = XA + llo*RS + lhi*8;
      #pragma unroll
      for (int kt = 0; kt < KT; ++kt){
        aL[kt] = *(const bf16x8*)(ar + kt*32);
        aH[kt] = *(const bf16x8*)(ar + 16*RS + kt*32);
      }
      f32x4 cL0 = {0.f,0.f,0.f,0.f}, cL1 = cL0, cL2 = cL0;
      f32x4 cH0 = cL0, cH1 = cL0, cH2 = cL0;
      #pragma unroll
      for (int m = 0; m < 3; ++m){
        const uint16_t* wb = Wl + (size_t)((m*NT + wave)*KT)*512 + lane*8;
        #pragma unroll
        for (int kt = 0; kt < KT; ++kt){
          bf16x8 w = *(const bf16x8*)(wb + kt*512);
          if (m == 0){ cL0 = __builtin_amdgcn_mfma_f32_16x16x32_bf16(aL[kt], w, cL0,0,0,0);
                       cH0 = __builtin_amdgcn_mfma_f32_16x16x32_bf16(aH[kt], w, cH0,0,0,0); }
          else if (m == 1){ cL1 = __builtin_amdgcn_mfma_f32_16x16x32_bf16(aL[kt], w, cL1,0,0,0);
                            cH1 = __builtin_amdgcn_mfma_f32_16x16x32_bf16(aH[kt], w, cH1,0,0,0); }
          else { cL2 = __builtin_amdgcn_mfma_f32_16x16x32_bf16(aL[kt], w, cL2,0,0,0);
                 cH2 = __builtin_amdgcn_mfma_f32_16x16x32_bf16(aH[kt], w, cH2,0,0,0); }
        }
      }
      // epilogue: gates; write own j-slice to ring (+ out for L2)
      const int j = nt*16 + llo;
      uint16_t* rs = RNG + (size_t)((t&3)*32)*RC;
      #pragma unroll
      for (int half = 0; half < 2; ++half){
        const f32x4& c0 = half ? cH0 : cL0;
        const f32x4& c1 = half ? cH1 : cL1;
        const f32x4& c2 = half ? cH2 : cL2;
        #pragma unroll
        for (int r = 0; r < 4; ++r){
          const int row = half*16 + lhi*4 + r;
          float ff1 = tanh_f(c0[r] + bs0);
          float ff2 = tanh_f(c1[r] + bs1);
          float tt  = sigm_f(c2[r] + bs2);
          float h = ff1 + tt*(ff2 - ff1);
          rs[(size_t)row*RC + j] = bfbits(h);
          if constexpr (LAYER == 2)
            out[((size_t)(b0+row)*T_ + t)*128 + j] = h;
          if (t == T_-1 && j < SCOL)
            out[OH + (size_t)(b0+row)*512 + CBASE + j] = h;
        }
      }
    }

    DRAIN();                       // all ring/out stores at L2
    __syncthreads();
    if (tid == 0){
      __threadfence();             // one wbl2: publish ring data to LLC
      __hip_atomic_store(&FLG[SID*16], t+2, __ATOMIC_RELEASE, __HIP_MEMORY_SCOPE_AGENT);
    }
  }
}

__global__ __launch_bounds__(512) void cfc_pipe(
    const float* __restrict__ elapsed, const float* __restrict__ enc,
    const float* __restrict__ b1_0, const float* __restrict__ b2_0,
    const float* __restrict__ ba0,  const float* __restrict__ bb0,
    const float* __restrict__ b1_1, const float* __restrict__ b2_1,
    const float* __restrict__ ba1,  const float* __restrict__ bb1,
    const float* __restrict__ b1_2, const float* __restrict__ b2_2,
    const float* __restrict__ ba2,  const float* __restrict__ bb2,
    const uint16_t* __restrict__ Wp, uint8_t* __restrict__ wsb,
    float* __restrict__ out)
{
  __shared__ uint16_t Wl[61440];       // 122880 B (max stage weight shard)
  __shared__ uint16_t XA[32*392];      // 25088 B  -> 147968 B total, 1 block/CU

  const int bid = blockIdx.x;
  const int g = bid & 15, s = bid >> 4;     // group's 9 stages share XCD g%8
  const int tid = threadIdx.x;

  switch (s){
    case 0: stage_run<0>(g, tid, elapsed, enc, b1_0, b2_0, ba0, bb0, Wp, wsb, out, Wl, XA); break;
    case 1: stage_run<1>(g, tid, elapsed, enc, b1_0, b2_0, ba0, bb0, Wp, wsb, out, Wl, XA); break;
    case 2: stage_run<2>(g, tid, elapsed, enc, b1_0, b2_0, ba0, bb0, Wp, wsb, out, Wl, XA); break;
    case 3: stage_run<3>(g, tid, elapsed, enc, b1_1, b2_1, ba1, bb1, Wp, wsb, out, Wl, XA); break;
    case 4: stage_run<4>(g, tid, elapsed, enc, b1_1, b2_1, ba1, bb1, Wp, wsb, out, Wl, XA); break;
    case 5: stage_run<5>(g, tid, elapsed, enc, b1_1, b2_1, ba1, bb1, Wp, wsb, out, Wl, XA); break;
    case 6: stage_run<6>(g, tid, elapsed, enc, b1_1, b2_1, ba1, bb1, Wp, wsb, out, Wl, XA); break;
    case 7: stage_run<7>(g, tid, elapsed, enc, b1_2, b2_2, ba2, bb2, Wp, wsb, out, Wl, XA); break;
    default: stage_run<8>(g, tid, elapsed, enc, b1_2, b2_2, ba2, bb2, Wp, wsb, out, Wl, XA); break;
  }
}

extern "C" void kernel_launch(void* const* d_in, const int* in_sizes, int n_in,
                              void* d_out, int out_size, void* d_ws, size_t ws_size,
                              hipStream_t stream)
{
  const float* elapsed = (const float*)d_in[0];
  const float* enc     = (const float*)d_in[1];
  const float* W1_0 = (const float*)d_in[2];  const float* b1_0 = (const float*)d_in[3];
  const float* W2_0 = (const float*)d_in[4];  const float* b2_0 = (const float*)d_in[5];
  const float* Wa0  = (const float*)d_in[6];  const float* ba0  = (const float*)d_in[7];
  const float* Wb0  = (const float*)d_in[8];  const float* bb0  = (const float*)d_in[9];
  const float* M0   = (const float*)d_in[10];
  const float* W1_1 = (const float*)d_in[11]; const float* b1_1 = (const float*)d_in[12];
  const float* W2_1 = (const float*)d_in[13]; const float* b2_1 = (const float*)d_in[14];
  const float* Wa1  = (const float*)d_in[15]; const float* ba1  = (const float*)d_in[16];
  const float* Wb1  = (const float*)d_in[17]; const float* bb1  = (const float*)d_in[18];
  const float* M1   = (const float*)d_in[19];
  const float* W1_2 = (const float*)d_in[20]; const float* b1_2 = (const float*)d_in[21];
  const float* W2_2 = (const float*)d_in[22]; const float* b2_2 = (const float*)d_in[23];
  const float* Wa2  = (const float*)d_in[24]; const float* ba2  = (const float*)d_in[25];
  const float* Wb2  = (const float*)d_in[26]; const float* bb2  = (const float*)d_in[27];
  const float* M2   = (const float*)d_in[28];

  uint8_t*  wsb = (uint8_t*)d_ws;
  uint16_t* wp  = (uint16_t*)d_ws;

  zero_flags<<<5, 512, 0, stream>>>(wsb);
  pack_w<<<90, 256, 0, stream>>>(W1_0, W2_0, Wa0, Wb0, M0, wp,          15,  8, 231, 232);
  pack_w<<<90, 256, 0, stream>>>(W1_1, W2_1, Wa1, Wb1, M1, wp + 184320, 10, 12, 153, 384);
  pack_w<<<54, 256, 0, stream>>>(W1_2, W2_2, Wa2, Wb2, M2, wp + 368640,  8,  9, 128, 281);

  cfc_pipe<<<144, 512, 0, stream>>>(elapsed, enc,
                                    b1_0, b2_0, ba0, bb0,
                                    b1_1, b2_1, ba1, bb1,
                                    b1_2, b2_2, ba2, bb2,
                                    wp, wsb, (float*)d_out);
}

// Round 9
// 3192.015 us; speedup vs baseline: 5.9357x; 1.6165x over previous
//
#include <hip/hip_runtime.h>
#include <stdint.h>

#define B_ 512
#define T_ 512

typedef __attribute__((ext_vector_type(8))) __bf16 bf16x8;
typedef __attribute__((ext_vector_type(4))) float f32x4;
typedef __attribute__((ext_vector_type(8))) unsigned short u16x8;

// d_ws layout (bytes):
//   [0)        packed bf16 weights (pack_w), 958464 u16 = 1916928 B
//   [N0OFF)    R0 ring: 16 groups x 4 slots x 32 rows x 240 cols u16 = 983040 B
//   [N1OFF)    R1 ring: 16 x 4 x 32 x 160 u16 = 655360 B
//   [N2OFF)    R2 ring: 16 x 4 x 32 x 128 u16 = 524288 B
//   [FLOFF)    flags: 16 groups x 9 stages x 16 ints (64B spaced) = 9216 B
#define N0OFF 1916928u
#define N1OFF 2899968u
#define N2OFF 3555328u
#define FLOFF 4079616u

// 9 stages per 32-row group: S0-2 = L0 tiles {0-4,5-9,10-14}; S3-6 = L1 tiles
// {0-2,3-5,6-7,8-9}; S7-8 = L2 tiles {0-3,4-7}. Weights live in LDS (loaded
// once). States flow through depth-4 rings; flag = completed step + 2.
// Protocol (R9): ring DATA stores are agent-scope (sc1) relaxed -> write
// through to LLC; producer drains vmcnt then RELAXED flag store (no wbl2).
// Consumer: relaxed polls + one ACQUIRE (buffer_inv) per step before staging.
constexpr int L_[9]   = {0,0,0, 1,1,1,1, 2,2};
constexpr int NT0_[9] = {0,5,10, 0,3,6,8, 0,4};
constexpr int NT_[9]  = {5,5,5, 3,3,2,2, 4,4};
constexpr int KT_[3]  = {8,12,9};
constexpr int NPT_[3] = {15,10,8};
constexpr int SC_[3]  = {231,153,128};
constexpr int RS_[3]  = {264,392,296};
constexpr int CB_[3]  = {0,231,384};
constexpr int RC_[3]  = {240,160,128};
constexpr unsigned WOFF_[3] = {0u,184320u,368640u};
// wait lists: flag index (stage within group) + lag (need flag >= t+lag)
constexpr int WN_[9] = {6,6,6, 8,8,8,8, 5,5};
constexpr int WF_[9][8] = {
  {1,2,3,4,5,6,0,0},{0,2,3,4,5,6,0,0},{0,1,3,4,5,6,0,0},
  {0,1,2,4,5,6,7,8},{0,1,2,3,5,6,7,8},{0,1,2,3,4,6,7,8},{0,1,2,3,4,5,7,8},
  {3,4,5,6,8,0,0,0},{3,4,5,6,7,0,0,0}};
constexpr int WL_[9][8] = {
  {1,1,-2,-2,-2,-2,0,0},{1,1,-2,-2,-2,-2,0,0},{1,1,-2,-2,-2,-2,0,0},
  {2,2,2,1,1,1,-2,-2},{2,2,2,1,1,1,-2,-2},{2,2,2,1,1,1,-2,-2},{2,2,2,1,1,1,-2,-2},
  {2,2,2,2,1,0,0,0},{2,2,2,2,1,0,0,0}};

static __device__ __forceinline__ uint16_t bfbits(float f){
  __bf16 h = (__bf16)f; return __builtin_bit_cast(uint16_t, h);
}
static __device__ __forceinline__ float sigm_f(float x){
  return __builtin_amdgcn_rcpf(1.0f + __builtin_amdgcn_exp2f(-1.4426950408889634f*x));
}
static __device__ __forceinline__ float tanh_f(float x){
  return 2.0f*__builtin_amdgcn_rcpf(1.0f + __builtin_amdgcn_exp2f(-2.8853900817779268f*x)) - 1.0f;
}
static __device__ __forceinline__ uint32_t ldg32(const uint32_t* p){
  return __hip_atomic_load(p, __ATOMIC_RELAXED, __HIP_MEMORY_SCOPE_AGENT);
}
static __device__ __forceinline__ uint16_t ldg16(const uint16_t* p){
  return __hip_atomic_load(p, __ATOMIC_RELAXED, __HIP_MEMORY_SCOPE_AGENT);
}
static __device__ __forceinline__ void stg16(uint16_t* p, uint16_t v){
  __hip_atomic_store(p, v, __ATOMIC_RELAXED, __HIP_MEMORY_SCOPE_AGENT);  // sc1: LLC write-through
}
#define DRAIN() asm volatile("s_waitcnt vmcnt(0)" ::: "memory")

__global__ void zero_flags(uint8_t* wsb){
  int i = blockIdx.x*512 + threadIdx.x;
  if (i < 2304) ((int*)(wsb + FLOFF))[i] = 0;
}

__global__ void pack_w(const float* __restrict__ W1, const float* __restrict__ W2,
                       const float* __restrict__ Wa, const float* __restrict__ Wb,
                       const float* __restrict__ Msk, uint16_t* __restrict__ dst,
                       int NPT, int KT, int S, int C)
{
  int c = blockIdx.x * 256 + threadIdx.x;
  int chunks = 3 * NPT * KT * 64;
  if (c >= chunks) return;
  int perN = KT * 64;
  int n3 = c / perN, r = c % perN;
  int kt = r >> 6, lane = r & 63;
  int m = n3 / NPT, nt = n3 % NPT;
  int j = nt * 16 + (lane & 15);
  int kb = kt * 32 + (lane >> 4) * 8;
  u16x8 o;
  #pragma unroll
  for (int i = 0; i < 8; ++i){
    int k = kb + i;
    float v = 0.f;
    if (j < S && k < C){
      size_t idx = (size_t)j * C + k;
      if (m == 0)      v = W1[idx] * Msk[idx];
      else if (m == 1) v = W2[idx] * Msk[idx];
      else             v = Wa[idx] + Wb[idx];
    }
    o[i] = bfbits(v);
  }
  *(u16x8*)(dst + (size_t)c * 8) = o;
}

template<int SID>
__device__ __forceinline__ void stage_run(
    int g, int tid,
    const float* __restrict__ elapsed, const float* __restrict__ enc,
    const float* __restrict__ bp1, const float* __restrict__ bp2,
    const float* __restrict__ bpa, const float* __restrict__ bpb,
    const uint16_t* __restrict__ Wp, uint8_t* __restrict__ wsb,
    float* __restrict__ out, uint16_t* Wl, uint16_t* XA)
{
  constexpr int LAYER = L_[SID];
  constexpr int NT0 = NT0_[SID], NT = NT_[SID];
  constexpr int KT = KT_[LAYER], NPT = NPT_[LAYER];
  constexpr int SCOL = SC_[LAYER], RS = RS_[LAYER];
  constexpr int CBASE = CB_[LAYER], RC = RC_[LAYER];

  const int wave = tid >> 6, lane = tid & 63, llo = lane & 15, lhi = lane >> 4;
  const int rowg = tid >> 4, cg = tid & 15;       // 32 rows x 16 threads
  const int b0 = g * 32;

  uint16_t* R0 = (uint16_t*)(wsb + N0OFF) + (size_t)g * (4*32*240);
  uint16_t* R1 = (uint16_t*)(wsb + N1OFF) + (size_t)g * (4*32*160);
  uint16_t* R2 = (uint16_t*)(wsb + N2OFF) + (size_t)g * (4*32*128);
  int* FLG = (int*)(wsb + FLOFF) + g * (9*16);
  uint16_t* RNG = (LAYER==0) ? R0 : (LAYER==1) ? R1 : R2;

  // ---- weights: global (packed) -> LDS, once ----
  {
    const u16x8* Wp8 = (const u16x8*)(Wp + WOFF_[LAYER]);
    u16x8* Wl8 = (u16x8*)Wl;
    constexpr int CHUNKS = 3 * NT * KT * 64;
    for (int c = tid; c < CHUNKS; c += 512){
      int m = c / (NT*KT*64), r = c - m*(NT*KT*64);
      int tl = r / (KT*64),  r2 = r - tl*(KT*64);
      Wl8[c] = Wp8[(size_t)((m*NPT + NT0 + tl)*KT*64) + r2];
    }
  }
  // ---- XA zero (K-pad columns must stay 0) ----
  for (int i = tid; i < 32*RS; i += 512) XA[i] = 0;

  // ---- biases -> registers (wave owns tile NT0+wave) ----
  float bs0 = 0.f, bs1 = 0.f, bs2 = 0.f;
  if (wave < NT){
    const int j = (NT0 + wave)*16 + llo;
    if (j < SCOL){ bs0 = bp1[j]; bs1 = bp2[j]; bs2 = bpa[j] + bpb[j]; }
  }

  // ---- init own h-slice (state -1) into ring slot 3 (sc1 stores) ----
  for (int idx = tid; idx < 32*NT*16; idx += 512){
    int row = idx / (NT*16), jl = idx % (NT*16);
    int j = NT0*16 + jl;
    float v = 0.f;
    if (j < SCOL){
      if constexpr (LAYER == 0) v = enc[(size_t)(b0+row)*512 + j];
      else if constexpr (LAYER == 1) v = enc[(size_t)(b0+row)*512 + 231 + j];
      else v = enc[(size_t)(b0+row)*512 + 384 + j];
    }
    stg16(&RNG[(size_t)(3*32 + row)*RC + j], bfbits(v));
  }
  DRAIN();
  __syncthreads();
  if (tid == 0){
    __threadfence();   // once, belt-and-braces for init
    __hip_atomic_store(&FLG[SID*16], 1, __ATOMIC_RELEASE, __HIP_MEMORY_SCOPE_AGENT);
  }

  const size_t OH = (size_t)B_ * T_ * 128;

  #pragma unroll 1
  for (int t = 0; t < T_; ++t){
    // ---- wait: batched relaxed polls, then one acquire (ordering inv) ----
    if (tid == 0){
      int spin = 0;
      for (;;){
        bool ok = true;
        #pragma unroll
        for (int i = 0; i < WN_[SID]; ++i){
          int v = __hip_atomic_load(&FLG[WF_[SID][i]*16], __ATOMIC_RELAXED,
                                    __HIP_MEMORY_SCOPE_AGENT);
          ok &= (v >= t + WL_[SID][i]);
        }
        if (ok) break;
        __builtin_amdgcn_s_sleep(2);
        if ((++spin & 15) == 0)   // staleness guard: periodic acquire
          (void)__hip_atomic_load(&FLG[WF_[SID][0]*16], __ATOMIC_ACQUIRE,
                                  __HIP_MEMORY_SCOPE_AGENT);
      }
      (void)__hip_atomic_load(&FLG[SID*16], __ATOMIC_ACQUIRE,
                              __HIP_MEMORY_SCOPE_AGENT);
    }
    __syncthreads();

    // ---- stage A-matrix into XA (sc1 ring loads: LLC-fresh) ----
    {
      uint16_t* dst = XA + rowg * RS;
      if constexpr (LAYER == 0){
        const uint16_t* src = R0 + (size_t)((((t+3)&3)*32) + rowg)*240;  // h0(t-1)
        const uint32_t* s32 = (const uint32_t*)src;
        for (int pc = cg; pc < 115; pc += 16){
          uint32_t v = ldg32(s32 + pc);
          dst[1 + 2*pc] = (uint16_t)v;
          dst[2 + 2*pc] = (uint16_t)(v >> 16);
        }
        if (cg == 0){
          dst[231] = ldg16(src + 230);
          dst[0] = bfbits(elapsed[(size_t)(b0 + rowg)*T_ + t]);          // x_t
        }
      } else if constexpr (LAYER == 1){
        const uint16_t* s0 = R0 + (size_t)(((t&3)*32) + rowg)*240;       // n0(t)
        const uint32_t* s032 = (const uint32_t*)s0;
        for (int pc = cg; pc < 115; pc += 16)
          *(uint32_t*)(dst + 2*pc) = ldg32(s032 + pc);
        const uint16_t* s1 = R1 + (size_t)((((t+3)&3)*32) + rowg)*160;   // h1(t-1)
        const uint32_t* s132 = (const uint32_t*)s1;
        for (int jc = cg; jc < 76; jc += 16){
          uint32_t v = ldg32(s132 + jc);
          dst[231 + 2*jc] = (uint16_t)v;
          dst[232 + 2*jc] = (uint16_t)(v >> 16);
        }
        if (cg == 0){
          dst[230] = ldg16(s0 + 230);
          dst[383] = ldg16(s1 + 152);
        }
      } else {
        const uint16_t* s1 = R1 + (size_t)(((t&3)*32) + rowg)*160;       // n1(t)
        const uint32_t* s132 = (const uint32_t*)s1;
        for (int jc = cg; jc < 76; jc += 16)
          *(uint32_t*)(dst + 2*jc) = ldg32(s132 + jc);
        const uint16_t* s2 = R2 + (size_t)((((t+3)&3)*32) + rowg)*128;   // h2(t-1)
        const uint32_t* s232 = (const uint32_t*)s2;
        for (int jc = cg; jc < 64; jc += 16){
          uint32_t v = ldg32(s232 + jc);
          dst[153 + 2*jc] = (uint16_t)v;
          dst[154 + 2*jc] = (uint16_t)(v >> 16);
        }
        if (cg == 0) dst[152] = ldg16(s1 + 152);
      }
    }
    __syncthreads();

    // ---- compute: wave owns tile NT0+wave (weights from LDS) ----
    if (wave < NT){
      const int nt = NT0 + wave;
      bf16x8 aL[KT], aH[KT];
      const uint16_t* ar = XA + llo*RS + lhi*8;
      #pragma unroll
      for (int kt = 0; kt < KT; ++kt){
        aL[kt] = *(const bf16x8*)(ar + kt*32);
        aH[kt] = *(const bf16x8*)(ar + 16*RS + kt*32);
      }
      f32x4 cL0 = {0.f,0.f,0.f,0.f}, cL1 = cL0, cL2 = cL0;
      f32x4 cH0 = cL0, cH1 = cL0, cH2 = cL0;
      #pragma unroll
      for (int m = 0; m < 3; ++m){
        const uint16_t* wb = Wl + (size_t)((m*NT + wave)*KT)*512 + lane*8;
        #pragma unroll
        for (int kt = 0; kt < KT; ++kt){
          bf16x8 w = *(const bf16x8*)(wb + kt*512);
          if (m == 0){ cL0 = __builtin_amdgcn_mfma_f32_16x16x32_bf16(aL[kt], w, cL0,0,0,0);
                       cH0 = __builtin_amdgcn_mfma_f32_16x16x32_bf16(aH[kt], w, cH0,0,0,0); }
          else if (m == 1){ cL1 = __builtin_amdgcn_mfma_f32_16x16x32_bf16(aL[kt], w, cL1,0,0,0);
                            cH1 = __builtin_amdgcn_mfma_f32_16x16x32_bf16(aH[kt], w, cH1,0,0,0); }
          else { cL2 = __builtin_amdgcn_mfma_f32_16x16x32_bf16(aL[kt], w, cL2,0,0,0);
                 cH2 = __builtin_amdgcn_mfma_f32_16x16x32_bf16(aH[kt], w, cH2,0,0,0); }
        }
      }
      // epilogue: gates; sc1 ring writes (+ out for L2)
      const int j = nt*16 + llo;
      uint16_t* rs = RNG + (size_t)((t&3)*32)*RC;
      #pragma unroll
      for (int half = 0; half < 2; ++half){
        const f32x4& c0 = half ? cH0 : cL0;
        const f32x4& c1 = half ? cH1 : cL1;
        const f32x4& c2 = half ? cH2 : cL2;
        #pragma unroll
        for (int r = 0; r < 4; ++r){
          const int row = half*16 + lhi*4 + r;
          float ff1 = tanh_f(c0[r] + bs0);
          float ff2 = tanh_f(c1[r] + bs1);
          float tt  = sigm_f(c2[r] + bs2);
          float h = ff1 + tt*(ff2 - ff1);
          stg16(&rs[(size_t)row*RC + j], bfbits(h));
          if constexpr (LAYER == 2)
            out[((size_t)(b0+row)*T_ + t)*128 + j] = h;
          if (t == T_-1 && j < SCOL)
            out[OH + (size_t)(b0+row)*512 + CBASE + j] = h;
        }
      }
    }

    DRAIN();                       // sc1 stores complete -> data at LLC
    __syncthreads();
    if (tid == 0)                  // relaxed flag: ordering via the drain
      __hip_atomic_store(&FLG[SID*16], t+2, __ATOMIC_RELAXED, __HIP_MEMORY_SCOPE_AGENT);
  }
}

__global__ __launch_bounds__(512) void cfc_pipe(
    const float* __restrict__ elapsed, const float* __restrict__ enc,
    const float* __restrict__ b1_0, const float* __restrict__ b2_0,
    const float* __restrict__ ba0,  const float* __restrict__ bb0,
    const float* __restrict__ b1_1, const float* __restrict__ b2_1,
    const float* __restrict__ ba1,  const float* __restrict__ bb1,
    const float* __restrict__ b1_2, const float* __restrict__ b2_2,
    const float* __restrict__ ba2,  const float* __restrict__ bb2,
    const uint16_t* __restrict__ Wp, uint8_t* __restrict__ wsb,
    float* __restrict__ out)
{
  __shared__ uint16_t Wl[61440];       // 122880 B (max stage weight shard)
  __shared__ uint16_t XA[32*392];      // 25088 B  -> 147968 B total, 1 block/CU

  const int bid = blockIdx.x;
  const int g = bid & 15, s = bid >> 4;     // group's 9 stages share XCD g%8
  const int tid = threadIdx.x;

  switch (s){
    case 0: stage_run<0>(g, tid, elapsed, enc, b1_0, b2_0, ba0, bb0, Wp, wsb, out, Wl, XA); break;
    case 1: stage_run<1>(g, tid, elapsed, enc, b1_0, b2_0, ba0, bb0, Wp, wsb, out, Wl, XA); break;
    case 2: stage_run<2>(g, tid, elapsed, enc, b1_0, b2_0, ba0, bb0, Wp, wsb, out, Wl, XA); break;
    case 3: stage_run<3>(g, tid, elapsed, enc, b1_1, b2_1, ba1, bb1, Wp, wsb, out, Wl, XA); break;
    case 4: stage_run<4>(g, tid, elapsed, enc, b1_1, b2_1, ba1, bb1, Wp, wsb, out, Wl, XA); break;
    case 5: stage_run<5>(g, tid, elapsed, enc, b1_1, b2_1, ba1, bb1, Wp, wsb, out, Wl, XA); break;
    case 6: stage_run<6>(g, tid, elapsed, enc, b1_1, b2_1, ba1, bb1, Wp, wsb, out, Wl, XA); break;
    case 7: stage_run<7>(g, tid, elapsed, enc, b1_2, b2_2, ba2, bb2, Wp, wsb, out, Wl, XA); break;
    default: stage_run<8>(g, tid, elapsed, enc, b1_2, b2_2, ba2, bb2, Wp, wsb, out, Wl, XA); break;
  }
}

extern "C" void kernel_launch(void* const* d_in, const int* in_sizes, int n_in,
                              void* d_out, int out_size, void* d_ws, size_t ws_size,
                              hipStream_t stream)
{
  const float* elapsed = (const float*)d_in[0];
  const float* enc     = (const float*)d_in[1];
  const float* W1_0 = (const float*)d_in[2];  const float* b1_0 = (const float*)d_in[3];
  const float* W2_0 = (const float*)d_in[4];  const float* b2_0 = (const float*)d_in[5];
  const float* Wa0  = (const float*)d_in[6];  const float* ba0  = (const float*)d_in[7];
  const float* Wb0  = (const float*)d_in[8];  const float* bb0  = (const float*)d_in[9];
  const float* M0   = (const float*)d_in[10];
  const float* W1_1 = (const float*)d_in[11]; const float* b1_1 = (const float*)d_in[12];
  const float* W2_1 = (const float*)d_in[13]; const float* b2_1 = (const float*)d_in[14];
  const float* Wa1  = (const float*)d_in[15]; const float* ba1  = (const float*)d_in[16];
  const float* Wb1  = (const float*)d_in[17]; const float* bb1  = (const float*)d_in[18];
  const float* M1   = (const float*)d_in[19];
  const float* W1_2 = (const float*)d_in[20]; const float* b1_2 = (const float*)d_in[21];
  const float* W2_2 = (const float*)d_in[22]; const float* b2_2 = (const float*)d_in[23];
  const float* Wa2  = (const float*)d_in[24]; const float* ba2  = (const float*)d_in[25];
  const float* Wb2  = (const float*)d_in[26]; const float* bb2  = (const float*)d_in[27];
  const float* M2   = (const float*)d_in[28];

  uint8_t*  wsb = (uint8_t*)d_ws;
  uint16_t* wp  = (uint16_t*)d_ws;

  zero_flags<<<5, 512, 0, stream>>>(wsb);
  pack_w<<<90, 256, 0, stream>>>(W1_0, W2_0, Wa0, Wb0, M0, wp,          15,  8, 231, 232);
  pack_w<<<90, 256, 0, stream>>>(W1_1, W2_1, Wa1, Wb1, M1, wp + 184320, 10, 12, 153, 384);
  pack_w<<<54, 256, 0, stream>>>(W1_2, W2_2, Wa2, Wb2, M2, wp + 368640,  8,  9, 128, 281);

  cfc_pipe<<<144, 512, 0, stream>>>(elapsed, enc,
                                    b1_0, b2_0, ba0, bb0,
                                    b1_1, b2_1, ba1, bb1,
                                    b1_2, b2_2, ba2, bb2,
                                    wp, wsb, (float*)d_out);
}